// Round 5
// baseline (72.143 us; speedup 1.0000x reference)
//
#include <hip/hip_runtime.h>

#define LOG2E 1.44269504088896340736f
#define LN2   0.69314718055994530942f

constexpr int BSZ = 2, SEQ = 2048, DM = 1024, DS = 16, DR = 64;
constexpr int NC = 64, CL = SEQ / NC;   // 64 chunks of 32

// Workspace layout (floats)
constexpr size_t OFF_DT   = 0;                                 // [4096][1024]
constexpr size_t OFF_BM   = OFF_DT   + (size_t)BSZ*SEQ*DM;     // [4096][16]
constexpr size_t OFF_CM   = OFF_BM   + (size_t)BSZ*SEQ*DS;     // [4096][16]
constexpr size_t OFF_S    = OFF_CM   + (size_t)BSZ*SEQ*DS;     // [B][NC][1024]
constexpr size_t OFF_HEND = OFF_S    + (size_t)BSZ*NC*DM;      // [B][NC][16][1024]
constexpr size_t OFF_HIN  = OFF_HEND + (size_t)BSZ*NC*DS*DM;   // [B][NC][16][1024]
constexpr size_t OFF_PART = OFF_HIN  + (size_t)BSZ*NC*DS*DM;   // [4][4096][32]

__device__ inline float softplusf(float z) {
  float e = __builtin_amdgcn_exp2f(z * LOG2E);
  if (z > 15.f) return z;
  if (z < -8.f) return e;                      // log1p(e) ~ e
  return __builtin_amdgcn_logf(1.f + e) * LN2; // v_log is log2
}

__device__ inline void fma4(float& acc, float4 a, float4 b) {
  acc = fmaf(a.x, b.x, fmaf(a.y, b.y, fmaf(a.z, b.z, fmaf(a.w, b.w, acc))));
}

// ================= K_front: dtproj (blocks 0..255) | bcm_part (blocks 256..511) ==========
__global__ __launch_bounds__(256, 2) void k_front(const float* __restrict__ inp,
                                                  const float* __restrict__ W,
                                                  const float* __restrict__ bias,
                                                  float* __restrict__ dt,
                                                  const float* __restrict__ x,
                                                  const float* __restrict__ BW,
                                                  const float* __restrict__ CW,
                                                  float* __restrict__ part) {
  __shared__ __align__(16) float smem[16896];   // 67.6 KB
  int bid = blockIdx.x;
  int t = threadIdx.x;
  if (bid < 256) {
    // dtproj: dt[4096x1024] = softplus(inp[4096x64] @ W[1024x64]^T + 2*bias)
    float* At = smem;              // [64][132] [k][m]
    float* Wt = smem + 64 * 132;   // [64][132] [k][n]
    int mt = bid >> 3, nt = bid & 7;
    int m0 = mt * 128, n0 = nt * 128;
#pragma unroll
    for (int i = 0; i < 8; ++i) {
      int idx4 = t + 256 * i;                   // 0..2047
      int m = idx4 >> 4, k4 = (idx4 & 15) * 4;
      float4 v = *(const float4*)&inp[(size_t)(m0 + m) * DR + k4];
      At[(k4 + 0) * 132 + m] = v.x; At[(k4 + 1) * 132 + m] = v.y;
      At[(k4 + 2) * 132 + m] = v.z; At[(k4 + 3) * 132 + m] = v.w;
    }
#pragma unroll
    for (int i = 0; i < 8; ++i) {
      int idx4 = t + 256 * i;
      int n = idx4 >> 4, k4 = (idx4 & 15) * 4;
      float4 v = *(const float4*)&W[(size_t)(n0 + n) * DR + k4];
      Wt[(k4 + 0) * 132 + n] = v.x; Wt[(k4 + 1) * 132 + n] = v.y;
      Wt[(k4 + 2) * 132 + n] = v.z; Wt[(k4 + 3) * 132 + n] = v.w;
    }
    __syncthreads();
    int mg = t >> 4, ng = t & 15;
    float acc[8][8] = {};
#pragma unroll 4
    for (int k = 0; k < 64; ++k) {
      const float* rowA = At + k * 132;
      const float* rowW = Wt + k * 132;
      float4 a0 = *(const float4*)&rowA[mg * 8];
      float4 a1 = *(const float4*)&rowA[mg * 8 + 4];
      float4 w0 = *(const float4*)&rowW[ng * 4];
      float4 w1 = *(const float4*)&rowW[ng * 4 + 64];
      float a[8] = {a0.x, a0.y, a0.z, a0.w, a1.x, a1.y, a1.z, a1.w};
      float w[8] = {w0.x, w0.y, w0.z, w0.w, w1.x, w1.y, w1.z, w1.w};
#pragma unroll
      for (int i = 0; i < 8; ++i)
#pragma unroll
        for (int j = 0; j < 8; ++j)
          acc[i][j] = fmaf(a[i], w[j], acc[i][j]);
    }
    float4 b0 = *(const float4*)&bias[n0 + ng * 4];
    float4 b1 = *(const float4*)&bias[n0 + ng * 4 + 64];
    float bb[8] = {b0.x, b0.y, b0.z, b0.w, b1.x, b1.y, b1.z, b1.w};
#pragma unroll
    for (int i = 0; i < 8; ++i) {
      int m = m0 + mg * 8 + i;
      float4 lo, hi;
      lo.x = softplusf(acc[i][0] + 2.f * bb[0]);
      lo.y = softplusf(acc[i][1] + 2.f * bb[1]);
      lo.z = softplusf(acc[i][2] + 2.f * bb[2]);
      lo.w = softplusf(acc[i][3] + 2.f * bb[3]);
      hi.x = softplusf(acc[i][4] + 2.f * bb[4]);
      hi.y = softplusf(acc[i][5] + 2.f * bb[5]);
      hi.z = softplusf(acc[i][6] + 2.f * bb[6]);
      hi.w = softplusf(acc[i][7] + 2.f * bb[7]);
      *(float4*)&dt[(size_t)m * DM + n0 + ng * 4]      = lo;
      *(float4*)&dt[(size_t)m * DM + n0 + ng * 4 + 64] = hi;
    }
  } else {
    // bcm: part[ks][4096][32], Mtile 64, Ksplit 4 (K=256 per block, 2 stages of 128)
    float* xt = smem;              // [64][132]
    float* wt = smem + 64 * 132;   // [32][132]
    int bid2 = bid - 256;
    int mt = bid2 >> 2, ks = bid2 & 3;
    int m0 = mt * 64, k0 = ks * 256;
    int lg = t >> 3, ng = t & 7;
    float acc[2][4] = {};
#pragma unroll
    for (int kh = 0; kh < 2; ++kh) {
      int kb = k0 + kh * 128;
      __syncthreads();
#pragma unroll
      for (int i = 0; i < 8; ++i) {   // 64 rows x 32 float4
        int idx4 = t + 256 * i;
        int r = idx4 >> 5, c4 = (idx4 & 31) * 4;
        *(float4*)&xt[r * 132 + c4] = *(const float4*)&x[(size_t)(m0 + r) * DM + kb + c4];
      }
#pragma unroll
      for (int i = 0; i < 4; ++i) {   // 32 rows x 32 float4
        int idx4 = t + 256 * i;
        int n = idx4 >> 5, c4 = (idx4 & 31) * 4;
        const float* src = (n < 16) ? &BW[(size_t)n * DM + kb + c4]
                                    : &CW[(size_t)(n - 16) * DM + kb + c4];
        *(float4*)&wt[n * 132 + c4] = *(const float4*)src;
      }
      __syncthreads();
#pragma unroll 4
      for (int k4 = 0; k4 < 32; ++k4) {
        float4 xa0 = *(const float4*)&xt[(lg * 2 + 0) * 132 + k4 * 4];
        float4 xa1 = *(const float4*)&xt[(lg * 2 + 1) * 132 + k4 * 4];
#pragma unroll
        for (int j = 0; j < 4; ++j) {
          float4 w = *(const float4*)&wt[(ng + 8 * j) * 132 + k4 * 4];
          fma4(acc[0][j], xa0, w);
          fma4(acc[1][j], xa1, w);
        }
      }
    }
#pragma unroll
    for (int i = 0; i < 2; ++i)
#pragma unroll
      for (int j = 0; j < 4; ++j)
        part[(size_t)ks * (4096 * 32) + (size_t)(m0 + lg * 2 + i) * 32 + ng + 8 * j] = acc[i][j];
  }
}

// ---------------- Phase 1: chunk-local scan, 8 states/thread (half-wave n-split) -------
// 2048 blocks x 128 thr: b=bid>>10, c=(bid>>4)&63, dg=bid&15; lane pairs (l, l^32) share d.
__global__ __launch_bounds__(128, 4) void k_phase1(const float* __restrict__ x,
                                                   const float* __restrict__ dt,
                                                   const float* __restrict__ part,
                                                   const float* __restrict__ A_log,
                                                   float* __restrict__ Bm,
                                                   float* __restrict__ Cm,
                                                   float* __restrict__ Ssum,
                                                   float* __restrict__ hend) {
  __shared__ float bml[CL * DS];  // 512 floats
  int bid = blockIdx.x;
  int b = bid >> 10, c = (bid >> 4) & 63, dg = bid & 15;
  int t = threadIdx.x;
  int lane = t & 63, w = t >> 6;
  int nh = lane >> 5;                       // which 8-state half
  int d = dg * 64 + (lane & 31) + w * 32;
  size_t blbase = (size_t)b * SEQ + c * CL;
  {
    // reduce split-K part -> bml (all blocks) and Bm/Cm (dg==0 only)
    int l = t >> 2, q = (t & 3) * 4;        // element t*4 of the 512-float tile
    size_t e = (blbase + l) * 32 + q;
    float4 sb = make_float4(0.f, 0.f, 0.f, 0.f), sc = sb;
#pragma unroll
    for (int ks = 0; ks < 4; ++ks) {
      float4 vb = *(const float4*)&part[(size_t)ks * (4096 * 32) + e];
      float4 vc = *(const float4*)&part[(size_t)ks * (4096 * 32) + e + 16];
      sb.x += vb.x; sb.y += vb.y; sb.z += vb.z; sb.w += vb.w;
      sc.x += vc.x; sc.y += vc.y; sc.z += vc.z; sc.w += vc.w;
    }
    *(float4*)&bml[t * 4] = sb;
    if (dg == 0) {
      *(float4*)&Bm[(blbase + l) * DS + q] = sb;
      *(float4*)&Cm[(blbase + l) * DS + q] = sc;
    }
  }
  __syncthreads();
  float a2[8];
#pragma unroll
  for (int j = 0; j < 8; ++j)
    a2[j] = -__builtin_amdgcn_exp2f(A_log[nh * 8 + j] * LOG2E) * LOG2E;
  float h[8] = {};
  float S = 0.f;
  size_t base = blbase * DM + d;
#pragma unroll 4
  for (int l = 0; l < CL; ++l) {
    float dtv = dt[base + (size_t)l * DM];
    float xv  = x[base + (size_t)l * DM];
    S += dtv;
    float dtx = dtv * xv;
    const float* bq = &bml[l * DS + nh * 8];
#pragma unroll
    for (int j = 0; j < 8; ++j) {
      float a = __builtin_amdgcn_exp2f(dtv * a2[j]);
      h[j] = fmaf(a, h[j], dtx * bq[j]);
    }
  }
  size_t cc = (size_t)b * NC + c;
  if (nh == 0) Ssum[cc * DM + d] = S;
#pragma unroll
  for (int j = 0; j < 8; ++j) hend[(cc * DS + nh * 8 + j) * DM + d] = h[j];
}

// ---------------- Phase 2: sequential scan over chunk summaries ----------------
// 256 blocks x 128 thr: b=bid>>7, n=(bid>>3)&15, dg=bid&7
__global__ __launch_bounds__(128, 4) void k_phase2(const float* __restrict__ A_log,
                                                   const float* __restrict__ Ssum,
                                                   const float* __restrict__ hend,
                                                   float* __restrict__ hin) {
  int bid = blockIdx.x;
  int b = bid >> 7, n = (bid >> 3) & 15, dg = bid & 7;
  int d = dg * 128 + threadIdx.x;
  float a2n = -__builtin_amdgcn_exp2f(A_log[n] * LOG2E) * LOG2E;
  float h = 0.f;
#pragma unroll 8
  for (int c = 0; c < NC; ++c) {
    size_t cc = (size_t)b * NC + c;
    hin[(cc * DS + n) * DM + d] = h;
    float aa = __builtin_amdgcn_exp2f(a2n * Ssum[cc * DM + d]);
    h = fmaf(aa, h, hend[(cc * DS + n) * DM + d]);
  }
}

// ---------------- Phase 3: re-run chunks from h_in, 8 states/thread, emit y ----------
__global__ __launch_bounds__(128, 4) void k_phase3(const float* __restrict__ x,
                                                   const float* __restrict__ dt,
                                                   const float* __restrict__ Bm,
                                                   const float* __restrict__ Cm,
                                                   const float* __restrict__ A_log,
                                                   const float* __restrict__ Dvec,
                                                   const float* __restrict__ hin,
                                                   float* __restrict__ out) {
  __shared__ float bml[CL * DS], cml[CL * DS];
  int bid = blockIdx.x;
  int b = bid >> 10, c = (bid >> 4) & 63, dg = bid & 15;
  int t = threadIdx.x;
  int lane = t & 63, w = t >> 6;
  int nh = lane >> 5;
  int d = dg * 64 + (lane & 31) + w * 32;
  size_t blbase = (size_t)b * SEQ + c * CL;
  *(float4*)&bml[t * 4] = *(const float4*)&Bm[blbase * DS + t * 4];
  *(float4*)&cml[t * 4] = *(const float4*)&Cm[blbase * DS + t * 4];
  __syncthreads();
  float a2[8];
#pragma unroll
  for (int j = 0; j < 8; ++j)
    a2[j] = -__builtin_amdgcn_exp2f(A_log[nh * 8 + j] * LOG2E) * LOG2E;
  size_t cc = (size_t)b * NC + c;
  float h[8];
#pragma unroll
  for (int j = 0; j < 8; ++j) h[j] = hin[(cc * DS + nh * 8 + j) * DM + d];
  float dvl = (nh == 0) ? Dvec[d] : 0.f;
  size_t base = blbase * DM + d;
#pragma unroll 4
  for (int l = 0; l < CL; ++l) {
    float dtv = dt[base + (size_t)l * DM];
    float xv  = x[base + (size_t)l * DM];
    float dtx = dtv * xv;
    const float* bq = &bml[l * DS + nh * 8];
    const float* cq = &cml[l * DS + nh * 8];
    float y0 = xv * dvl, y1 = 0.f;
#pragma unroll
    for (int j = 0; j < 4; ++j) {
      float a = __builtin_amdgcn_exp2f(dtv * a2[j]);
      h[j] = fmaf(a, h[j], dtx * bq[j]);
      y0 = fmaf(h[j], cq[j], y0);
    }
#pragma unroll
    for (int j = 4; j < 8; ++j) {
      float a = __builtin_amdgcn_exp2f(dtv * a2[j]);
      h[j] = fmaf(a, h[j], dtx * bq[j]);
      y1 = fmaf(h[j], cq[j], y1);
    }
    float y = y0 + y1;
    y += __shfl_xor(y, 32);
    if (nh == 0) out[base + (size_t)l * DM] = y;
  }
}

extern "C" void kernel_launch(void* const* d_in, const int* in_sizes, int n_in,
                              void* d_out, int out_size, void* d_ws, size_t ws_size,
                              hipStream_t stream) {
  (void)in_sizes; (void)n_in; (void)out_size; (void)ws_size;
  const float* x     = (const float*)d_in[0];
  const float* dtp   = (const float*)d_in[1];
  const float* A_log = (const float*)d_in[2];
  const float* dtW   = (const float*)d_in[3];
  const float* dtb   = (const float*)d_in[4];
  const float* BW    = (const float*)d_in[5];
  const float* CW    = (const float*)d_in[6];
  const float* Dv    = (const float*)d_in[7];
  float* out = (float*)d_out;
  float* ws  = (float*)d_ws;

  float* dt   = ws + OFF_DT;
  float* Bm   = ws + OFF_BM;
  float* Cm   = ws + OFF_CM;
  float* S    = ws + OFF_S;
  float* hend = ws + OFF_HEND;
  float* hin  = ws + OFF_HIN;
  float* part = ws + OFF_PART;

  k_front <<<512,  256, 0, stream>>>(dtp, dtW, dtb, dt, x, BW, CW, part);
  k_phase1<<<2048, 128, 0, stream>>>(x, dt, part, A_log, Bm, Cm, S, hend);
  k_phase2<<<256,  128, 0, stream>>>(A_log, S, hend, hin);
  k_phase3<<<2048, 128, 0, stream>>>(x, dt, Bm, Cm, A_log, Dv, hin, out);
}

// Round 6
// 64.763 us; speedup vs baseline: 1.1140x; 1.1140x over previous
//
#include <hip/hip_runtime.h>
#include <hip/hip_cooperative_groups.h>

namespace cg = cooperative_groups;

#define LOG2E 1.44269504088896340736f
#define LN2   0.69314718055994530942f

constexpr int BSZ = 2, SEQ = 2048, DM = 1024, DS = 16, DR = 64;
// fallback decomposition
constexpr int NC = 64, CL = SEQ / NC;     // 64 chunks of 32
// fused (cooperative) decomposition
constexpr int NCF = 128, CLF = SEQ / NCF; // 128 chunks of 16

// Workspace layout (floats) — regions disjoint, shared by both paths
constexpr size_t OFF_DT   = 0;                                  // [4096][1024]
constexpr size_t OFF_BM   = OFF_DT   + (size_t)BSZ*SEQ*DM;      // [4096][16]
constexpr size_t OFF_CM   = OFF_BM   + (size_t)BSZ*SEQ*DS;      // [4096][16]
constexpr size_t OFF_S    = OFF_CM   + (size_t)BSZ*SEQ*DS;      // [B][NCF][1024] (max)
constexpr size_t OFF_HEND = OFF_S    + (size_t)BSZ*NCF*DM;      // [B][NCF][16][1024] (max)
constexpr size_t OFF_HIN  = OFF_HEND + (size_t)BSZ*NCF*DS*DM;   // [B][NCF][16][1024] (max)
constexpr size_t OFF_PART = OFF_HIN  + (size_t)BSZ*NCF*DS*DM;   // [4][4096][32]
// total ~ 13.6M floats = 54 MB (ws is 256 MiB)

__device__ inline float softplusf(float z) {
  float e = __builtin_amdgcn_exp2f(z * LOG2E);
  if (z > 15.f) return z;
  if (z < -8.f) return e;                      // log1p(e) ~ e
  return __builtin_amdgcn_logf(1.f + e) * LN2; // v_log is log2
}

__device__ inline void fma4(float& acc, float4 a, float4 b) {
  acc = fmaf(a.x, b.x, fmaf(a.y, b.y, fmaf(a.z, b.z, fmaf(a.w, b.w, acc))));
}

// ================= K_front: dtproj (blocks 0..255) | bcm_part (blocks 256..511) ==========
__global__ __launch_bounds__(256, 2) void k_front(const float* __restrict__ inp,
                                                  const float* __restrict__ W,
                                                  const float* __restrict__ bias,
                                                  float* __restrict__ dt,
                                                  const float* __restrict__ x,
                                                  const float* __restrict__ BW,
                                                  const float* __restrict__ CW,
                                                  float* __restrict__ part) {
  __shared__ __align__(16) float smem[16896];   // 67.6 KB
  int bid = blockIdx.x;
  int t = threadIdx.x;
  if (bid < 256) {
    float* At = smem;              // [64][132] [k][m]
    float* Wt = smem + 64 * 132;   // [64][132] [k][n]
    int mt = bid >> 3, nt = bid & 7;
    int m0 = mt * 128, n0 = nt * 128;
#pragma unroll
    for (int i = 0; i < 8; ++i) {
      int idx4 = t + 256 * i;                   // 0..2047
      int m = idx4 >> 4, k4 = (idx4 & 15) * 4;
      float4 v = *(const float4*)&inp[(size_t)(m0 + m) * DR + k4];
      At[(k4 + 0) * 132 + m] = v.x; At[(k4 + 1) * 132 + m] = v.y;
      At[(k4 + 2) * 132 + m] = v.z; At[(k4 + 3) * 132 + m] = v.w;
    }
#pragma unroll
    for (int i = 0; i < 8; ++i) {
      int idx4 = t + 256 * i;
      int n = idx4 >> 4, k4 = (idx4 & 15) * 4;
      float4 v = *(const float4*)&W[(size_t)(n0 + n) * DR + k4];
      Wt[(k4 + 0) * 132 + n] = v.x; Wt[(k4 + 1) * 132 + n] = v.y;
      Wt[(k4 + 2) * 132 + n] = v.z; Wt[(k4 + 3) * 132 + n] = v.w;
    }
    __syncthreads();
    int mg = t >> 4, ng = t & 15;
    float acc[8][8] = {};
#pragma unroll 4
    for (int k = 0; k < 64; ++k) {
      const float* rowA = At + k * 132;
      const float* rowW = Wt + k * 132;
      float4 a0 = *(const float4*)&rowA[mg * 8];
      float4 a1 = *(const float4*)&rowA[mg * 8 + 4];
      float4 w0 = *(const float4*)&rowW[ng * 4];
      float4 w1 = *(const float4*)&rowW[ng * 4 + 64];
      float a[8] = {a0.x, a0.y, a0.z, a0.w, a1.x, a1.y, a1.z, a1.w};
      float w[8] = {w0.x, w0.y, w0.z, w0.w, w1.x, w1.y, w1.z, w1.w};
#pragma unroll
      for (int i = 0; i < 8; ++i)
#pragma unroll
        for (int j = 0; j < 8; ++j)
          acc[i][j] = fmaf(a[i], w[j], acc[i][j]);
    }
    float4 b0 = *(const float4*)&bias[n0 + ng * 4];
    float4 b1 = *(const float4*)&bias[n0 + ng * 4 + 64];
    float bb[8] = {b0.x, b0.y, b0.z, b0.w, b1.x, b1.y, b1.z, b1.w};
#pragma unroll
    for (int i = 0; i < 8; ++i) {
      int m = m0 + mg * 8 + i;
      float4 lo, hi;
      lo.x = softplusf(acc[i][0] + 2.f * bb[0]);
      lo.y = softplusf(acc[i][1] + 2.f * bb[1]);
      lo.z = softplusf(acc[i][2] + 2.f * bb[2]);
      lo.w = softplusf(acc[i][3] + 2.f * bb[3]);
      hi.x = softplusf(acc[i][4] + 2.f * bb[4]);
      hi.y = softplusf(acc[i][5] + 2.f * bb[5]);
      hi.z = softplusf(acc[i][6] + 2.f * bb[6]);
      hi.w = softplusf(acc[i][7] + 2.f * bb[7]);
      *(float4*)&dt[(size_t)m * DM + n0 + ng * 4]      = lo;
      *(float4*)&dt[(size_t)m * DM + n0 + ng * 4 + 64] = hi;
    }
  } else {
    float* xt = smem;              // [64][132]
    float* wt = smem + 64 * 132;   // [32][132]
    int bid2 = bid - 256;
    int mt = bid2 >> 2, ks = bid2 & 3;
    int m0 = mt * 64, k0 = ks * 256;
    int lg = t >> 3, ng = t & 7;
    float acc[2][4] = {};
#pragma unroll
    for (int kh = 0; kh < 2; ++kh) {
      int kb = k0 + kh * 128;
      __syncthreads();
#pragma unroll
      for (int i = 0; i < 8; ++i) {
        int idx4 = t + 256 * i;
        int r = idx4 >> 5, c4 = (idx4 & 31) * 4;
        *(float4*)&xt[r * 132 + c4] = *(const float4*)&x[(size_t)(m0 + r) * DM + kb + c4];
      }
#pragma unroll
      for (int i = 0; i < 4; ++i) {
        int idx4 = t + 256 * i;
        int n = idx4 >> 5, c4 = (idx4 & 31) * 4;
        const float* src = (n < 16) ? &BW[(size_t)n * DM + kb + c4]
                                    : &CW[(size_t)(n - 16) * DM + kb + c4];
        *(float4*)&wt[n * 132 + c4] = *(const float4*)src;
      }
      __syncthreads();
#pragma unroll 4
      for (int k4 = 0; k4 < 32; ++k4) {
        float4 xa0 = *(const float4*)&xt[(lg * 2 + 0) * 132 + k4 * 4];
        float4 xa1 = *(const float4*)&xt[(lg * 2 + 1) * 132 + k4 * 4];
#pragma unroll
        for (int j = 0; j < 4; ++j) {
          float4 w = *(const float4*)&wt[(ng + 8 * j) * 132 + k4 * 4];
          fma4(acc[0][j], xa0, w);
          fma4(acc[1][j], xa1, w);
        }
      }
    }
#pragma unroll
    for (int i = 0; i < 2; ++i)
#pragma unroll
      for (int j = 0; j < 4; ++j)
        part[(size_t)ks * (4096 * 32) + (size_t)(m0 + lg * 2 + i) * 32 + ng + 8 * j] = acc[i][j];
  }
}

// ================= Fused cooperative scan: NCF=128 chunks of CLF=16 =================
// 1024 blocks x 256 thr = exactly 4 blocks/CU; __launch_bounds__(256,4) caps VGPR<=128.
// A: part->bml/cml (LDS), local scan keeping Tl/yl in regs, write Ssum/hend
// B: 512 blocks' wave 0: sequential chunk-summary scan -> hin
// C: y = yl + sum_n cml*hn*exp2(a2[n]*Tl)
__global__ __launch_bounds__(256, 4) void k_scan_fused(const float* __restrict__ x,
                                                       const float* __restrict__ dtg,
                                                       const float* __restrict__ part,
                                                       const float* __restrict__ A_log,
                                                       const float* __restrict__ Dv,
                                                       float* __restrict__ Ssum,
                                                       float* __restrict__ hend,
                                                       float* __restrict__ hin,
                                                       float* __restrict__ out) {
  cg::grid_group grid = cg::this_grid();
  __shared__ float bml[CLF * DS], cml[CLF * DS];   // 256 + 256 floats
  int bid = blockIdx.x, t = threadIdx.x;
  int b = bid >> 9, c = (bid >> 2) & 127, dg = bid & 3;
  int d = dg * 256 + t;
  size_t blbase = (size_t)b * SEQ + (size_t)c * CLF;
  size_t cc = (size_t)b * NCF + c;

  // ---- Phase A: reduce split-K partials into LDS tiles ----
  {
    int idx = t & 127, l = idx >> 3, pr = idx & 7;
    int col = pr * 2 + ((t >= 128) ? 16 : 0);
    size_t e = (blbase + l) * 32 + col;
    float2 s = make_float2(0.f, 0.f);
#pragma unroll
    for (int ks = 0; ks < 4; ++ks) {
      float2 v = *(const float2*)&part[(size_t)ks * (4096 * 32) + e];
      s.x += v.x; s.y += v.y;
    }
    float* dst = (t < 128) ? bml : cml;
    *(float2*)&dst[l * DS + pr * 2] = s;
  }
  __syncthreads();
  float a2[16];
#pragma unroll
  for (int n = 0; n < 16; ++n)
    a2[n] = -__builtin_amdgcn_exp2f(A_log[n] * LOG2E) * LOG2E;  // A[n]*log2(e)
  float Tl[CLF], yl[CLF], h[16] = {};
  float dv = Dv[d];
  float T = 0.f;
  size_t base = blbase * DM + d;
#pragma unroll
  for (int l = 0; l < CLF; ++l) {
    float dtv = dtg[base + (size_t)l * DM];
    float xv  = x[base + (size_t)l * DM];
    T += dtv; Tl[l] = T;
    float dtx = dtv * xv;
    float y = xv * dv;
    float bq[16], cq[16];
#pragma unroll
    for (int u = 0; u < 4; ++u) {
      *(float4*)&bq[4 * u] = *(const float4*)&bml[l * DS + 4 * u];
      *(float4*)&cq[4 * u] = *(const float4*)&cml[l * DS + 4 * u];
    }
#pragma unroll
    for (int n = 0; n < 16; ++n) {
      float a = __builtin_amdgcn_exp2f(dtv * a2[n]);
      h[n] = fmaf(a, h[n], dtx * bq[n]);
      y = fmaf(h[n], cq[n], y);
    }
    yl[l] = y;
  }
  Ssum[cc * DM + d] = T;
#pragma unroll
  for (int n = 0; n < 16; ++n) hend[(cc * DS + n) * DM + d] = h[n];

  grid.sync();

  // ---- Phase B: chunk-summary scan (512 blocks, wave 0 only) ----
  if (bid < 512 && t < 64) {
    int b2 = bid >> 8, n = (bid >> 4) & 15, ds16 = bid & 15;
    int d2 = ds16 * 64 + t;
    float a2n = -__builtin_amdgcn_exp2f(A_log[n] * LOG2E) * LOG2E;
    float hh = 0.f;
#pragma unroll 8
    for (int c2 = 0; c2 < NCF; ++c2) {
      size_t cc2 = (size_t)b2 * NCF + c2;
      hin[(cc2 * DS + n) * DM + d2] = hh;
      float aa = __builtin_amdgcn_exp2f(a2n * Ssum[cc2 * DM + d2]);
      hh = fmaf(aa, hh, hend[(cc2 * DS + n) * DM + d2]);
    }
  }

  grid.sync();

  // ---- Phase C: closed-form correction + store ----
  float hn[16];
#pragma unroll
  for (int n = 0; n < 16; ++n) hn[n] = hin[(cc * DS + n) * DM + d];
#pragma unroll
  for (int l = 0; l < CLF; ++l) {
    float y = yl[l];
#pragma unroll
    for (int u = 0; u < 4; ++u) {
      float4 cq = *(const float4*)&cml[l * DS + 4 * u];
      y = fmaf(cq.x * hn[4 * u + 0], __builtin_amdgcn_exp2f(a2[4 * u + 0] * Tl[l]), y);
      y = fmaf(cq.y * hn[4 * u + 1], __builtin_amdgcn_exp2f(a2[4 * u + 1] * Tl[l]), y);
      y = fmaf(cq.z * hn[4 * u + 2], __builtin_amdgcn_exp2f(a2[4 * u + 2] * Tl[l]), y);
      y = fmaf(cq.w * hn[4 * u + 3], __builtin_amdgcn_exp2f(a2[4 * u + 3] * Tl[l]), y);
    }
    out[base + (size_t)l * DM] = y;
  }
}

// ================= Fallback path (proven R3 kernels, NC=64/CL=32) =================
__global__ __launch_bounds__(256) void k_phase1(const float* __restrict__ x,
                                                const float* __restrict__ dt,
                                                const float* __restrict__ part,
                                                const float* __restrict__ A_log,
                                                float* __restrict__ Bm,
                                                float* __restrict__ Cm,
                                                float* __restrict__ Ssum,
                                                float* __restrict__ hend) {
  __shared__ float bml[CL * DS];
  int bid = blockIdx.x;
  int b = bid >> 8, c = (bid >> 2) & 63, dg = bid & 3;
  int t = threadIdx.x;
  int d = dg * 256 + t;
  size_t blbase = (size_t)b * SEQ + c * CL;
  {
    size_t e = (blbase + (t >> 3)) * 32 + 2 * (t & 7);
    float2 sb = make_float2(0.f, 0.f), sc = make_float2(0.f, 0.f);
#pragma unroll
    for (int ks = 0; ks < 4; ++ks) {
      float2 vb = *(const float2*)&part[(size_t)ks * (4096 * 32) + e];
      float2 vc = *(const float2*)&part[(size_t)ks * (4096 * 32) + e + 16];
      sb.x += vb.x; sb.y += vb.y; sc.x += vc.x; sc.y += vc.y;
    }
    *(float2*)&bml[t * 2] = sb;
    if (dg == 0) {
      *(float2*)&Bm[(blbase + (t >> 3)) * DS + 2 * (t & 7)] = sb;
      *(float2*)&Cm[(blbase + (t >> 3)) * DS + 2 * (t & 7)] = sc;
    }
  }
  __syncthreads();
  float a2[16];
#pragma unroll
  for (int n = 0; n < 16; ++n)
    a2[n] = -__builtin_amdgcn_exp2f(A_log[n] * LOG2E) * LOG2E;
  float h[16] = {};
  float S = 0.f;
  size_t base = blbase * DM + d;
#pragma unroll 4
  for (int l = 0; l < CL; ++l) {
    float dtv = dt[base + (size_t)l * DM];
    float xv  = x[base + (size_t)l * DM];
    S += dtv;
    float dtx = dtv * xv;
#pragma unroll
    for (int n = 0; n < 16; ++n) {
      float a = __builtin_amdgcn_exp2f(dtv * a2[n]);
      h[n] = fmaf(a, h[n], dtx * bml[l * DS + n]);
    }
  }
  size_t cc = (size_t)b * NC + c;
  Ssum[cc * DM + d] = S;
#pragma unroll
  for (int n = 0; n < 16; ++n) hend[(cc * DS + n) * DM + d] = h[n];
}

__global__ __launch_bounds__(256) void k_phase2(const float* __restrict__ A_log,
                                                const float* __restrict__ Ssum,
                                                const float* __restrict__ hend,
                                                float* __restrict__ hin) {
  int bid = blockIdx.x;
  int b = bid >> 6, n = (bid >> 2) & 15, dg = bid & 3;
  int d = dg * 256 + threadIdx.x;
  float a2n = -__builtin_amdgcn_exp2f(A_log[n] * LOG2E) * LOG2E;
  float h = 0.f;
#pragma unroll 8
  for (int c = 0; c < NC; ++c) {
    size_t cc = (size_t)b * NC + c;
    hin[(cc * DS + n) * DM + d] = h;
    float aa = __builtin_amdgcn_exp2f(a2n * Ssum[cc * DM + d]);
    h = fmaf(aa, h, hend[(cc * DS + n) * DM + d]);
  }
}

__global__ __launch_bounds__(256) void k_phase3(const float* __restrict__ x,
                                                const float* __restrict__ dt,
                                                const float* __restrict__ Bm,
                                                const float* __restrict__ Cm,
                                                const float* __restrict__ A_log,
                                                const float* __restrict__ Dvec,
                                                const float* __restrict__ hin,
                                                float* __restrict__ out) {
  __shared__ float bml[CL * DS], cml[CL * DS];
  int bid = blockIdx.x;
  int b = bid >> 8, c = (bid >> 2) & 63, dg = bid & 3;
  int t = threadIdx.x;
  int d = dg * 256 + t;
  const float* bsrc = Bm + ((size_t)b * SEQ + c * CL) * DS;
  const float* csrc = Cm + ((size_t)b * SEQ + c * CL) * DS;
  *(float2*)&bml[t * 2] = *(const float2*)&bsrc[t * 2];
  *(float2*)&cml[t * 2] = *(const float2*)&csrc[t * 2];
  __syncthreads();
  float a2[16];
#pragma unroll
  for (int n = 0; n < 16; ++n)
    a2[n] = -__builtin_amdgcn_exp2f(A_log[n] * LOG2E) * LOG2E;
  size_t cc = (size_t)b * NC + c;
  float h[16];
#pragma unroll
  for (int n = 0; n < 16; ++n) h[n] = hin[(cc * DS + n) * DM + d];
  float dv = Dvec[d];
  size_t base = ((size_t)b * SEQ + c * CL) * DM + d;
#pragma unroll 4
  for (int l = 0; l < CL; ++l) {
    float dtv = dt[base + (size_t)l * DM];
    float xv  = x[base + (size_t)l * DM];
    float dtx = dtv * xv;
    float y = 0.f;
#pragma unroll
    for (int n = 0; n < 16; ++n) {
      float a = __builtin_amdgcn_exp2f(dtv * a2[n]);
      h[n] = fmaf(a, h[n], dtx * bml[l * DS + n]);
      y = fmaf(h[n], cml[l * DS + n], y);
    }
    out[base + (size_t)l * DM] = fmaf(xv, dv, y);
  }
}

extern "C" void kernel_launch(void* const* d_in, const int* in_sizes, int n_in,
                              void* d_out, int out_size, void* d_ws, size_t ws_size,
                              hipStream_t stream) {
  (void)in_sizes; (void)n_in; (void)out_size; (void)ws_size;
  const float* x     = (const float*)d_in[0];
  const float* dtp   = (const float*)d_in[1];
  const float* A_log = (const float*)d_in[2];
  const float* dtW   = (const float*)d_in[3];
  const float* dtb   = (const float*)d_in[4];
  const float* BW    = (const float*)d_in[5];
  const float* CW    = (const float*)d_in[6];
  const float* Dv    = (const float*)d_in[7];
  float* out = (float*)d_out;
  float* ws  = (float*)d_ws;

  float* dt   = ws + OFF_DT;
  float* Bm   = ws + OFF_BM;
  float* Cm   = ws + OFF_CM;
  float* S    = ws + OFF_S;
  float* hend = ws + OFF_HEND;
  float* hin  = ws + OFF_HIN;
  float* part = ws + OFF_PART;

  k_front<<<512, 256, 0, stream>>>(dtp, dtW, dtb, dt, x, BW, CW, part);

  // Cooperative fused scan if co-residency is guaranteed; else proven 3-kernel path.
  int nb = 0;
  hipError_t oe = hipOccupancyMaxActiveBlocksPerMultiprocessor(&nb, k_scan_fused, 256, 0);
  bool coop_ok = (oe == hipSuccess && nb >= 4);
  if (coop_ok) {
    const float* xx = x; const float* dd = dt; const float* pp = part;
    const float* al = A_log; const float* dv = Dv;
    float* ss = S; float* he = hend; float* hi = hin; float* oo = out;
    void* kargs[] = {(void*)&xx, (void*)&dd, (void*)&pp, (void*)&al, (void*)&dv,
                     (void*)&ss, (void*)&he, (void*)&hi, (void*)&oo};
    hipError_t le = hipLaunchCooperativeKernel((const void*)k_scan_fused,
                                               dim3(1024), dim3(256), kargs, 0, stream);
    if (le == hipSuccess) return;
  }
  k_phase1<<<512, 256, 0, stream>>>(x, dt, part, A_log, Bm, Cm, S, hend);
  k_phase2<<<128, 256, 0, stream>>>(A_log, S, hend, hin);
  k_phase3<<<512, 256, 0, stream>>>(x, dt, Bm, Cm, A_log, Dv, hin, out);
}